// Round 13
// baseline (159.967 us; speedup 1.0000x reference)
//
#include <hip/hip_runtime.h>
#include <cfloat>

// Problem constants: L=6, N=16384, C=8, F=128, H=128
#define LL 6
#define NN 16384
#define CC 8
#define FF 128
#define HH 128
#define BN 16   // nodes per block (level kernel)

typedef __bf16 bf16x8 __attribute__((ext_vector_type(8)));
typedef __attribute__((ext_vector_type(4))) float f32x4;

static __device__ inline unsigned short f2bfbits(float f) {
    return __builtin_bit_cast(unsigned short, (__bf16)f);
}
static __device__ inline float bfbits2f(unsigned short b) {
    return (float)__builtin_bit_cast(__bf16, b);
}
// tanh(x) = 1 - 2/(e^{2x}+1); saturates correctly at +/-inf.
static __device__ inline float fast_tanh(float x) {
    const float e = __expf(2.0f * x);
    return 1.0f - __fdividef(2.0f, e + 1.0f);
}

// byte-offset swizzle for 256B-stride rows (breaks bank conflicts)
#define SWZ(row, byte) ((unsigned)(((row) * 256 + (byte)) ^ (((row) & 7) << 4)))

// extract mask byte for node 0..15 from the block's 16-byte mask vector
static __device__ inline int mbyte(const uint4 m, int node) {
    const int wsel = node >> 2;           // == wave for node = w*4 + 0..3
    const unsigned word = (wsel == 0) ? m.x : (wsel == 1) ? m.y
                        : (wsel == 2) ? m.z : m.w;
    return (int)((word >> ((node & 3) * 8)) & 0xFFu);
}

__device__ inline unsigned char make_maskbyte(const unsigned char* raw,
                                              int n, int f_i32) {
    if (f_i32) {
        const uint4 v0 = *(const uint4*)(raw + (size_t)n * 32);
        const uint4 v1 = *(const uint4*)(raw + (size_t)n * 32 + 16);
        return (v0.x ? 1 : 0) | (v0.y ? 2 : 0) | (v0.z ? 4 : 0) | (v0.w ? 8 : 0)
             | (v1.x ? 16 : 0) | (v1.y ? 32 : 0) | (v1.z ? 64 : 0) | (v1.w ? 128 : 0);
    } else {
        const unsigned a = *(const unsigned*)(raw + (size_t)n * 8);
        const unsigned c = *(const unsigned*)(raw + (size_t)n * 8 + 4);
        return ((a & 0xFFu) ? 1 : 0) | ((a & 0xFF00u) ? 2 : 0)
             | ((a & 0xFF0000u) ? 4 : 0) | ((a >> 24) ? 8 : 0)
             | ((c & 0xFFu) ? 16 : 0) | ((c & 0xFF00u) ? 32 : 0)
             | ((c & 0xFF0000u) ? 64 : 0) | ((c >> 24) ? 128 : 0);
    }
}

// ---------------------------------------------------------------------------
// Prologue, one launch: per-block mask-layout detect (all blocks scan the
// same 2 KB -> identical answer), per-node 8-bit masks, weight packing into
// MFMA B-frag order (split hi/lo bf16). B-frag (16x16x32): lane l holds
// B[k][n], n=l&15, k=8*(l>>4)+i.
// ---------------------------------------------------------------------------
__global__ __launch_bounds__(256) void prologue_kernel(
    const unsigned char* __restrict__ mask_raw,
    const float* __restrict__ Wg, const float* __restrict__ Wih,
    const float* __restrict__ Whh,
    const float* __restrict__ bih, const float* __restrict__ bhh,
    unsigned char* __restrict__ mbits,
    unsigned short* __restrict__ WgHi, unsigned short* __restrict__ WgLo,
    unsigned short* __restrict__ WdHi, unsigned short* __restrict__ WdLo,
    float* __restrict__ bias) {
    __shared__ int s_any;
    const int tid = threadIdx.x;
    if (tid == 0) s_any = 0;
    __syncthreads();
    {
        const unsigned a = ((const unsigned*)mask_raw)[tid * 2 + 0];
        const unsigned b = ((const unsigned*)mask_raw)[tid * 2 + 1];
        if (((a | b) & 0xFFFFFF00u) != 0) atomicOr(&s_any, 1);
    }
    __syncthreads();
    const int f_i32 = s_any ? 0 : 1;

    const int g = blockIdx.x * 256 + tid;
    if (g < LL * NN) mbits[g] = make_maskbyte(mask_raw, g, f_i32);

    if (g < 2048) {                      // Wg: (nt*4+kt)*64+lane == g
        const int l = g & 63;
        const int nt = g >> 8;
        const int kt = (g >> 6) & 3;
        const int n = nt * 16 + (l & 15);
        const int kb = kt * 32 + (l >> 4) * 8;
        #pragma unroll
        for (int i = 0; i < 8; ++i) {
            const float v = Wg[(kb + i) * HH + n];
            const unsigned short hb = f2bfbits(v);
            WgHi[g * 8 + i] = hb;
            WgLo[g * 8 + i] = f2bfbits(v - bfbits2f(hb));
        }
    } else if (g < 6144) {               // Wd: u = (nt*8+kt)*64+lane
        const int u = g - 2048;
        const int l = u & 63;
        const int nt = u >> 9;
        const int kt = (u >> 6) & 7;
        const int n = nt * 16 + (l & 15);
        const int kb = (kt & 3) * 32 + (l >> 4) * 8;
        const float* W = (kt < 4) ? Wih : Whh;
        #pragma unroll
        for (int i = 0; i < 8; ++i) {
            const float v = W[(kb + i) * HH + n];
            const unsigned short hb = f2bfbits(v);
            WdHi[u * 8 + i] = hb;
            WdLo[u * 8 + i] = f2bfbits(v - bfbits2f(hb));
        }
    } else if (g < 6272) {
        const int n = g - 6144;
        bias[n] = bih[n] + bhh[n];
    }
}

// ---------------------------------------------------------------------------
// One level, fused. Block: 256 threads = 4 waves; BN=16 nodes.
// NO staging barrier: mask bytes arrive as one broadcast uint4, cidx and A_c
// are wave-uniform scalar loads straight from global (wave w only touches
// its own 4 nodes -- LDS staging bought zero sharing and serialized the
// gathers behind the slowest staging load).
// x loads first (32 B/lane in flight across all of phase A).
// Phase A: 2 passes x 2 nodes, gathers batched back-to-back; 8x8 fp32 mix
// (A_c @ (ch@Wg) == (A_c@ch)@Wg), relu + masked maxpool -> pooled split-bf16
// in LDS (the only cross-wave handoff).
// GEMM-D: [x|pooled] @ [Wih;Whh] split-bf16 -> h = tanh(.) (registers).
// Epilogue: h -> h_out (final level) or Hp_out = h @ Wg via LDS transpose.
// Kernel boundary = device-wide sync (grid.sync measured 4.4x slower on the
// 8-XCD MI355X: per-sync L2 flush write amplification).
// __launch_bounds__(256,4): cap VGPR at 128 so the grid's 4 blocks/CU stay
// co-resident (grid-limited occupancy).
// ---------------------------------------------------------------------------
__global__ __launch_bounds__(256, 4) void level_kernel(
    const float* __restrict__ x_l, const int* __restrict__ cidx_l,
    const unsigned char* __restrict__ mbits_l,
    const float* __restrict__ Hp_in, const float* __restrict__ a_l,
    const unsigned short* __restrict__ WgHi, const unsigned short* __restrict__ WgLo,
    const unsigned short* __restrict__ WdHi, const unsigned short* __restrict__ WdLo,
    const float* __restrict__ bias,
    float* __restrict__ h_out,                // nullptr for intermediate levels
    float* __restrict__ Hp_out)               // nullptr for last level
{
    __shared__ __align__(16) unsigned char pH[BN * 256];   // pooled/h hi
    __shared__ __align__(16) unsigned char pL[BN * 256];   // pooled/h lo

    const int tid = threadIdx.x;
    const int lane = tid & 63;
    const int w = tid >> 6;
    const int lrow = lane & 15, lgrp = lane >> 4;
    const long nbase = (long)blockIdx.x * BN;

    // --- x loads first: 32 B/lane in flight across phase A ---
    float4 xr[8];
    #pragma unroll
    for (int kt = 0; kt < 4; ++kt) {
        const float* src = &x_l[(nbase + lrow) * FF + kt * 32 + lgrp * 8];
        xr[kt * 2 + 0] = *(const float4*)src;
        xr[kt * 2 + 1] = *(const float4*)(src + 4);
    }

    // --- block mask bytes: one broadcast 16B load, no LDS, no barrier ---
    const uint4 mball = *(const uint4*)(mbits_l + nbase);
    const int any = (mball.x | mball.y | mball.z | mball.w) != 0;

    // --- Phase A: 2 passes x 2 nodes; gathers for both nodes issue first ---
    if (any) {
        #pragma unroll
        for (int pass = 0; pass < 2; ++pass) {
            const int nodeA = w * 4 + pass * 2;
            const int nodeB = nodeA + 1;
            const int mbA = mbyte(mball, nodeA);   // wave-uniform
            const int mbB = mbyte(mball, nodeB);
            const int* ciA = cidx_l + (nbase + nodeA) * CC;   // uniform rows
            const int* ciB = cidx_l + (nbase + nodeB) * CC;
            float a0[CC], a1[CC], b0[CC], b1[CC];
            #pragma unroll
            for (int c = 0; c < CC; ++c) {
                a0[c] = 0.f; a1[c] = 0.f; b0[c] = 0.f; b1[c] = 0.f;
            }
            #pragma unroll
            for (int c = 0; c < CC; ++c) {         // all gathers back-to-back
                if (mbA & (1 << c)) {
                    const float2 v = *(const float2*)&Hp_in[(size_t)ciA[c] * HH + 2 * lane];
                    a0[c] = v.x; a1[c] = v.y;
                }
                if (mbB & (1 << c)) {
                    const float2 v = *(const float2*)&Hp_in[(size_t)ciB[c] * HH + 2 * lane];
                    b0[c] = v.x; b1[c] = v.y;
                }
            }
            // mixes: A_c coefficients are wave-uniform scalar-cache loads
            const float* aAp = a_l + (nbase + nodeA) * CC * CC;
            const float* aBp = a_l + (nbase + nodeB) * CC * CC;
            float mA0 = 0.f, mA1 = 0.f, mB0 = 0.f, mB1 = 0.f;
            if (mbA) {
                float m0 = -FLT_MAX, m1 = -FLT_MAX;
                #pragma unroll
                for (int c = 0; c < CC; ++c) {
                    if (mbA & (1 << c)) {
                        float s0 = 0.f, s1 = 0.f;
                        #pragma unroll
                        for (int d = 0; d < CC; ++d) {
                            const float av = aAp[c * CC + d];
                            s0 += av * a0[d]; s1 += av * a1[d];
                        }
                        m0 = fmaxf(m0, fmaxf(s0, 0.f));
                        m1 = fmaxf(m1, fmaxf(s1, 0.f));
                    }
                }
                mA0 = m0; mA1 = m1;
            }
            if (mbB) {
                float m0 = -FLT_MAX, m1 = -FLT_MAX;
                #pragma unroll
                for (int c = 0; c < CC; ++c) {
                    if (mbB & (1 << c)) {
                        float s0 = 0.f, s1 = 0.f;
                        #pragma unroll
                        for (int d = 0; d < CC; ++d) {
                            const float av = aBp[c * CC + d];
                            s0 += av * b0[d]; s1 += av * b1[d];
                        }
                        m0 = fmaxf(m0, fmaxf(s0, 0.f));
                        m1 = fmaxf(m1, fmaxf(s1, 0.f));
                    }
                }
                mB0 = m0; mB1 = m1;
            }
            {
                const unsigned short h0 = f2bfbits(mA0);
                const unsigned short h1 = f2bfbits(mA1);
                const unsigned short l0 = f2bfbits(mA0 - bfbits2f(h0));
                const unsigned short l1 = f2bfbits(mA1 - bfbits2f(h1));
                const unsigned off = SWZ(nodeA, lane * 4);   // cols 2l, 2l+1
                *(unsigned*)&pH[off] = (unsigned)h0 | ((unsigned)h1 << 16);
                *(unsigned*)&pL[off] = (unsigned)l0 | ((unsigned)l1 << 16);
            }
            {
                const unsigned short h0 = f2bfbits(mB0);
                const unsigned short h1 = f2bfbits(mB1);
                const unsigned short l0 = f2bfbits(mB0 - bfbits2f(h0));
                const unsigned short l1 = f2bfbits(mB1 - bfbits2f(h1));
                const unsigned off = SWZ(nodeB, lane * 4);
                *(unsigned*)&pH[off] = (unsigned)h0 | ((unsigned)h1 << 16);
                *(unsigned*)&pL[off] = (unsigned)l0 | ((unsigned)l1 << 16);
            }
        }
        __syncthreads();   // pooled handoff (the only cross-wave dependency)
    }

    // --- GEMM-D: h = tanh([x|pooled] @ [Wih;Whh] + b), split-bf16 ---
    bf16x8 ah[8], al[8];
    #pragma unroll
    for (int kt = 0; kt < 4; ++kt) {   // x part from preloaded registers
        const float4 v0 = xr[kt * 2 + 0];
        const float4 v1 = xr[kt * 2 + 1];
        const float vv[8] = {v0.x, v0.y, v0.z, v0.w, v1.x, v1.y, v1.z, v1.w};
        bf16x8 hfr, lfr;
        #pragma unroll
        for (int i = 0; i < 8; ++i) {
            const __bf16 hb = (__bf16)vv[i];
            hfr[i] = hb;
            lfr[i] = (__bf16)(vv[i] - (float)hb);
        }
        ah[kt] = hfr; al[kt] = lfr;
    }
    if (any) {
        #pragma unroll
        for (int kt = 4; kt < 8; ++kt) {
            const unsigned off = SWZ(lrow, (kt - 4) * 64 + lgrp * 16);
            ah[kt] = *(const bf16x8*)&pH[off];
            al[kt] = *(const bf16x8*)&pL[off];
        }
    }
    float hv[2][4];
    #pragma unroll
    for (int nn = 0; nn < 2; ++nn) {
        const int nt = w * 2 + nn;
        f32x4 acc = {0.f, 0.f, 0.f, 0.f};
        #pragma unroll
        for (int kt = 0; kt < 4; ++kt) {
            const bf16x8 bh = *(const bf16x8*)&WdHi[((nt * 8 + kt) * 64 + lane) * 8];
            const bf16x8 bl = *(const bf16x8*)&WdLo[((nt * 8 + kt) * 64 + lane) * 8];
            acc = __builtin_amdgcn_mfma_f32_16x16x32_bf16(ah[kt], bh, acc, 0, 0, 0);
            acc = __builtin_amdgcn_mfma_f32_16x16x32_bf16(ah[kt], bl, acc, 0, 0, 0);
            acc = __builtin_amdgcn_mfma_f32_16x16x32_bf16(al[kt], bh, acc, 0, 0, 0);
        }
        if (any) {
            #pragma unroll
            for (int kt = 4; kt < 8; ++kt) {
                const bf16x8 bh = *(const bf16x8*)&WdHi[((nt * 8 + kt) * 64 + lane) * 8];
                const bf16x8 bl = *(const bf16x8*)&WdLo[((nt * 8 + kt) * 64 + lane) * 8];
                acc = __builtin_amdgcn_mfma_f32_16x16x32_bf16(ah[kt], bh, acc, 0, 0, 0);
                acc = __builtin_amdgcn_mfma_f32_16x16x32_bf16(ah[kt], bl, acc, 0, 0, 0);
                acc = __builtin_amdgcn_mfma_f32_16x16x32_bf16(al[kt], bh, acc, 0, 0, 0);
            }
        }
        const float b = bias[nt * 16 + lrow];
        #pragma unroll
        for (int r = 0; r < 4; ++r)
            hv[nn][r] = fast_tanh(acc[r] + b);
    }

    if (h_out != nullptr) {
        #pragma unroll
        for (int nn = 0; nn < 2; ++nn) {
            const int nt = w * 2 + nn;
            #pragma unroll
            for (int r = 0; r < 4; ++r)
                h_out[(nbase + lgrp * 4 + r) * HH + nt * 16 + lrow] = hv[nn][r];
        }
    }
    if (Hp_out != nullptr) {
        // epilogue: Hp_next = h @ Wg via LDS transpose (pH/pL reused)
        __syncthreads();
        #pragma unroll
        for (int nn = 0; nn < 2; ++nn) {
            #pragma unroll
            for (int r = 0; r < 4; ++r) {
                const int row = lgrp * 4 + r;               // node in block
                const int col = (w * 2 + nn) * 16 + lrow;   // h column
                const unsigned short hb = f2bfbits(hv[nn][r]);
                const unsigned short lb = f2bfbits(hv[nn][r] - bfbits2f(hb));
                const unsigned off = SWZ(row, col * 2);
                *(unsigned short*)&pH[off] = hb;
                *(unsigned short*)&pL[off] = lb;
            }
        }
        __syncthreads();
        bf16x8 aHh[4], aLh[4];
        #pragma unroll
        for (int kt = 0; kt < 4; ++kt) {
            const unsigned off = SWZ(lrow, kt * 64 + lgrp * 16);
            aHh[kt] = *(const bf16x8*)&pH[off];
            aLh[kt] = *(const bf16x8*)&pL[off];
        }
        #pragma unroll
        for (int nn = 0; nn < 2; ++nn) {
            const int nt = w * 2 + nn;
            f32x4 acc = {0.f, 0.f, 0.f, 0.f};
            #pragma unroll
            for (int kt = 0; kt < 4; ++kt) {
                const bf16x8 bh = *(const bf16x8*)&WgHi[((nt * 4 + kt) * 64 + lane) * 8];
                const bf16x8 bl = *(const bf16x8*)&WgLo[((nt * 4 + kt) * 64 + lane) * 8];
                acc = __builtin_amdgcn_mfma_f32_16x16x32_bf16(aHh[kt], bh, acc, 0, 0, 0);
                acc = __builtin_amdgcn_mfma_f32_16x16x32_bf16(aHh[kt], bl, acc, 0, 0, 0);
                acc = __builtin_amdgcn_mfma_f32_16x16x32_bf16(aLh[kt], bh, acc, 0, 0, 0);
            }
            #pragma unroll
            for (int r = 0; r < 4; ++r)
                Hp_out[(nbase + lgrp * 4 + r) * HH + nt * 16 + lrow] = acc[r];
        }
    }
}

extern "C" void kernel_launch(void* const* d_in, const int* in_sizes, int n_in,
                              void* d_out, int out_size, void* d_ws, size_t ws_size,
                              hipStream_t stream) {
    const float* nf   = (const float*)d_in[0];
    const int*   cidx = (const int*)d_in[1];
    const unsigned char* mraw = (const unsigned char*)d_in[2];
    const float* A_c  = (const float*)d_in[3];
    const float* Wg   = (const float*)d_in[4];
    const float* Wih  = (const float*)d_in[5];
    const float* Whh  = (const float*)d_in[6];
    const float* bih  = (const float*)d_in[7];
    const float* bhh  = (const float*)d_in[8];
    float* outp = (float*)d_out;

    char* ws = (char*)d_ws;
    unsigned char* mbits = (unsigned char*)ws;                               // 96 KB
    unsigned short* WgHi = (unsigned short*)(ws + (128 << 10));              // 32 KB
    unsigned short* WgLo = (unsigned short*)(ws + (160 << 10));              // 32 KB
    unsigned short* WdHi = (unsigned short*)(ws + (192 << 10));              // 64 KB
    unsigned short* WdLo = (unsigned short*)(ws + (256 << 10));              // 64 KB
    float* bias          = (float*)(ws + (320 << 10));                       // 512 B
    float* HpA           = (float*)(ws + (1 << 20));                         // 8 MB
    float* HpB           = (float*)(ws + (1 << 20) + (8 << 20));             // 8 MB

    prologue_kernel<<<(LL * NN) / 256, 256, 0, stream>>>(
        mraw, Wg, Wih, Whh, bih, bhh, mbits, WgHi, WgLo, WdHi, WdLo, bias);

    // Levels reversed; s=0 (level L-1) has all-false masks -> Hp_in unread
    // (any==0 everywhere). Epilogue of level s writes Hp for level s+1 into
    // the other Hp buffer (ping-pong). Intermediate h never hits global.
    for (int s = 0; s < LL; ++s) {
        const int l = LL - 1 - s;
        float* hp_in  = (s & 1) ? HpB : HpA;
        float* hp_out = (s & 1) ? HpA : HpB;
        level_kernel<<<NN / BN, 256, 0, stream>>>(
            nf   + (size_t)l * NN * FF,
            cidx + (size_t)l * NN * CC,
            mbits + (size_t)l * NN,
            hp_in,
            A_c  + (size_t)l * NN * CC * CC,
            WgHi, WgLo, WdHi, WdLo, bias,
            (s == LL - 1) ? outp : nullptr,
            (s == LL - 1) ? nullptr : hp_out);
    }
}

// Round 14
// 129.955 us; speedup vs baseline: 1.2309x; 1.2309x over previous
//
#include <hip/hip_runtime.h>
#include <cfloat>

// Problem constants: L=6, N=16384, C=8, F=128, H=128
#define LL 6
#define NN 16384
#define CC 8
#define FF 128
#define HH 128
#define BN 16   // nodes per block (level kernel)

typedef __bf16 bf16x8 __attribute__((ext_vector_type(8)));
typedef __attribute__((ext_vector_type(4))) float f32x4;

static __device__ inline unsigned short f2bfbits(float f) {
    return __builtin_bit_cast(unsigned short, (__bf16)f);
}
static __device__ inline float bfbits2f(unsigned short b) {
    return (float)__builtin_bit_cast(__bf16, b);
}
// tanh(x) = 1 - 2/(e^{2x}+1); saturates correctly at +/-inf.
static __device__ inline float fast_tanh(float x) {
    const float e = __expf(2.0f * x);
    return 1.0f - __fdividef(2.0f, e + 1.0f);
}

// byte-offset swizzle for 256B-stride rows (breaks bank conflicts)
#define SWZ(row, byte) ((unsigned)(((row) * 256 + (byte)) ^ (((row) & 7) << 4)))

__device__ inline unsigned char make_maskbyte(const unsigned char* raw,
                                              int n, int f_i32) {
    if (f_i32) {
        const uint4 v0 = *(const uint4*)(raw + (size_t)n * 32);
        const uint4 v1 = *(const uint4*)(raw + (size_t)n * 32 + 16);
        return (v0.x ? 1 : 0) | (v0.y ? 2 : 0) | (v0.z ? 4 : 0) | (v0.w ? 8 : 0)
             | (v1.x ? 16 : 0) | (v1.y ? 32 : 0) | (v1.z ? 64 : 0) | (v1.w ? 128 : 0);
    } else {
        const unsigned a = *(const unsigned*)(raw + (size_t)n * 8);
        const unsigned c = *(const unsigned*)(raw + (size_t)n * 8 + 4);
        return ((a & 0xFFu) ? 1 : 0) | ((a & 0xFF00u) ? 2 : 0)
             | ((a & 0xFF0000u) ? 4 : 0) | ((a >> 24) ? 8 : 0)
             | ((c & 0xFFu) ? 16 : 0) | ((c & 0xFF00u) ? 32 : 0)
             | ((c & 0xFF0000u) ? 64 : 0) | ((c >> 24) ? 128 : 0);
    }
}

// ---------------------------------------------------------------------------
// Prologue, one launch: per-block mask-layout detect (all blocks scan the
// same 2 KB -> identical answer), per-node 8-bit masks, weight packing into
// MFMA B-frag order (split hi/lo bf16). B-frag (16x16x32): lane l holds
// B[k][n], n=l&15, k=8*(l>>4)+i.
// ---------------------------------------------------------------------------
__global__ __launch_bounds__(256) void prologue_kernel(
    const unsigned char* __restrict__ mask_raw,
    const float* __restrict__ Wg, const float* __restrict__ Wih,
    const float* __restrict__ Whh,
    const float* __restrict__ bih, const float* __restrict__ bhh,
    unsigned char* __restrict__ mbits,
    unsigned short* __restrict__ WgHi, unsigned short* __restrict__ WgLo,
    unsigned short* __restrict__ WdHi, unsigned short* __restrict__ WdLo,
    float* __restrict__ bias) {
    __shared__ int s_any;
    const int tid = threadIdx.x;
    if (tid == 0) s_any = 0;
    __syncthreads();
    {
        const unsigned a = ((const unsigned*)mask_raw)[tid * 2 + 0];
        const unsigned b = ((const unsigned*)mask_raw)[tid * 2 + 1];
        if (((a | b) & 0xFFFFFF00u) != 0) atomicOr(&s_any, 1);
    }
    __syncthreads();
    const int f_i32 = s_any ? 0 : 1;

    const int g = blockIdx.x * 256 + tid;
    if (g < LL * NN) mbits[g] = make_maskbyte(mask_raw, g, f_i32);

    if (g < 2048) {                      // Wg: (nt*4+kt)*64+lane == g
        const int l = g & 63;
        const int nt = g >> 8;
        const int kt = (g >> 6) & 3;
        const int n = nt * 16 + (l & 15);
        const int kb = kt * 32 + (l >> 4) * 8;
        #pragma unroll
        for (int i = 0; i < 8; ++i) {
            const float v = Wg[(kb + i) * HH + n];
            const unsigned short hb = f2bfbits(v);
            WgHi[g * 8 + i] = hb;
            WgLo[g * 8 + i] = f2bfbits(v - bfbits2f(hb));
        }
    } else if (g < 6144) {               // Wd: u = (nt*8+kt)*64+lane
        const int u = g - 2048;
        const int l = u & 63;
        const int nt = u >> 9;
        const int kt = (u >> 6) & 7;
        const int n = nt * 16 + (l & 15);
        const int kb = (kt & 3) * 32 + (l >> 4) * 8;
        const float* W = (kt < 4) ? Wih : Whh;
        #pragma unroll
        for (int i = 0; i < 8; ++i) {
            const float v = W[(kb + i) * HH + n];
            const unsigned short hb = f2bfbits(v);
            WdHi[u * 8 + i] = hb;
            WdLo[u * 8 + i] = f2bfbits(v - bfbits2f(hb));
        }
    } else if (g < 6272) {
        const int n = g - 6144;
        bias[n] = bih[n] + bhh[n];
    }
}

// ---------------------------------------------------------------------------
// One level, fused. Block: 256 threads = 4 waves; BN=16 nodes.
// x loads issued FIRST (overlap staging + phase A -- latency-bound kernel).
// Phase A in 2 passes of 2 nodes: both nodes' Hp gathers issue back-to-back,
// then both mixes (8x8 fp32; A_c @ (ch@Wg) == (A_c@ch)@Wg), relu + masked
// maxpool -> pooled split-bf16 in LDS.
// GEMM-D: [x|pooled] @ [Wih;Whh] split-bf16 -> h = tanh(.) (registers).
// Epilogue: h -> h_out (final level only) or Hp_out = h @ Wg split-bf16 via
// LDS transpose. Kernel boundary = the device-wide sync (grid.sync measured
// 4.4x slower on 8-XCD MI355X: per-sync L2 flush write amplification).
// Hp_in == nullptr marks the first processed level (all masks false):
// skip ALL phase-A staging (A_c read, cidx, maskbyte, barrier) -- kernel-arg
// uniform branch, no divergence.
// __launch_bounds__(256,4): cap VGPR at 128 so the grid's 4 blocks/CU stay
// co-resident (grid-limited occupancy).
// ---------------------------------------------------------------------------
__global__ __launch_bounds__(256, 4) void level_kernel(
    const float* __restrict__ x_l, const int* __restrict__ cidx_l,
    const unsigned char* __restrict__ mbits_l,
    const float* __restrict__ Hp_in, const float* __restrict__ a_l,
    const unsigned short* __restrict__ WgHi, const unsigned short* __restrict__ WgLo,
    const unsigned short* __restrict__ WdHi, const unsigned short* __restrict__ WdLo,
    const float* __restrict__ bias,
    float* __restrict__ h_out,                // nullptr for intermediate levels
    float* __restrict__ Hp_out)               // nullptr for last level
{
    __shared__ __align__(16) unsigned char pH[BN * 256];   // pooled/h hi
    __shared__ __align__(16) unsigned char pL[BN * 256];   // pooled/h lo
    __shared__ float a_lds[BN][CC][CC];
    __shared__ int   cidx_lds[BN][CC];
    __shared__ __align__(16) unsigned char maskbyte[BN];

    const int tid = threadIdx.x;
    const int lane = tid & 63;
    const int w = tid >> 6;
    const int lrow = lane & 15, lgrp = lane >> 4;
    const long nbase = (long)blockIdx.x * BN;
    const bool has_prev = (Hp_in != nullptr);   // kernel-arg uniform

    // --- x loads first: 32 B/lane in flight across staging + phase A ---
    float4 xr[8];
    #pragma unroll
    for (int kt = 0; kt < 4; ++kt) {
        const float* src = &x_l[(nbase + lrow) * FF + kt * 32 + lgrp * 8];
        xr[kt * 2 + 0] = *(const float4*)src;
        xr[kt * 2 + 1] = *(const float4*)(src + 4);
    }

    int any = 0;
    if (has_prev) {
        ((float4*)a_lds)[tid] = ((const float4*)(a_l + nbase * CC * CC))[tid];
        if (tid < 32)
            ((uint4*)cidx_lds)[tid] = ((const uint4*)(cidx_l + nbase * CC))[tid];
        if (tid < BN) maskbyte[tid] = mbits_l[nbase + tid];
        __syncthreads();
        const uint4 mball = *(const uint4*)maskbyte;
        any = (mball.x | mball.y | mball.z | mball.w) != 0;
    }

    // --- Phase A: 2 passes x 2 nodes; gathers for both nodes issue first ---
    if (any) {
        #pragma unroll
        for (int pass = 0; pass < 2; ++pass) {
            const int nodeA = w * 4 + pass * 2;
            const int nodeB = nodeA + 1;
            const int mbA = maskbyte[nodeA];     // wave-uniform
            const int mbB = maskbyte[nodeB];
            float a0[CC], a1[CC], b0[CC], b1[CC];
            #pragma unroll
            for (int c = 0; c < CC; ++c) {
                a0[c] = 0.f; a1[c] = 0.f; b0[c] = 0.f; b1[c] = 0.f;
            }
            #pragma unroll
            for (int c = 0; c < CC; ++c) {       // all gathers back-to-back
                if (mbA & (1 << c)) {
                    const float2 v = *(const float2*)&Hp_in[(size_t)cidx_lds[nodeA][c] * HH + 2 * lane];
                    a0[c] = v.x; a1[c] = v.y;
                }
                if (mbB & (1 << c)) {
                    const float2 v = *(const float2*)&Hp_in[(size_t)cidx_lds[nodeB][c] * HH + 2 * lane];
                    b0[c] = v.x; b1[c] = v.y;
                }
            }
            // mixes (consume after both nodes' loads are in flight)
            float mA0 = 0.f, mA1 = 0.f, mB0 = 0.f, mB1 = 0.f;
            if (mbA) {
                float m0 = -FLT_MAX, m1 = -FLT_MAX;
                #pragma unroll
                for (int c = 0; c < CC; ++c) {
                    if (mbA & (1 << c)) {
                        float s0 = 0.f, s1 = 0.f;
                        #pragma unroll
                        for (int d = 0; d < CC; ++d) {
                            const float av = a_lds[nodeA][c][d];
                            s0 += av * a0[d]; s1 += av * a1[d];
                        }
                        m0 = fmaxf(m0, fmaxf(s0, 0.f));
                        m1 = fmaxf(m1, fmaxf(s1, 0.f));
                    }
                }
                mA0 = m0; mA1 = m1;
            }
            if (mbB) {
                float m0 = -FLT_MAX, m1 = -FLT_MAX;
                #pragma unroll
                for (int c = 0; c < CC; ++c) {
                    if (mbB & (1 << c)) {
                        float s0 = 0.f, s1 = 0.f;
                        #pragma unroll
                        for (int d = 0; d < CC; ++d) {
                            const float av = a_lds[nodeB][c][d];
                            s0 += av * b0[d]; s1 += av * b1[d];
                        }
                        m0 = fmaxf(m0, fmaxf(s0, 0.f));
                        m1 = fmaxf(m1, fmaxf(s1, 0.f));
                    }
                }
                mB0 = m0; mB1 = m1;
            }
            {
                const unsigned short h0 = f2bfbits(mA0);
                const unsigned short h1 = f2bfbits(mA1);
                const unsigned short l0 = f2bfbits(mA0 - bfbits2f(h0));
                const unsigned short l1 = f2bfbits(mA1 - bfbits2f(h1));
                const unsigned off = SWZ(nodeA, lane * 4);   // cols 2l, 2l+1
                *(unsigned*)&pH[off] = (unsigned)h0 | ((unsigned)h1 << 16);
                *(unsigned*)&pL[off] = (unsigned)l0 | ((unsigned)l1 << 16);
            }
            {
                const unsigned short h0 = f2bfbits(mB0);
                const unsigned short h1 = f2bfbits(mB1);
                const unsigned short l0 = f2bfbits(mB0 - bfbits2f(h0));
                const unsigned short l1 = f2bfbits(mB1 - bfbits2f(h1));
                const unsigned off = SWZ(nodeB, lane * 4);
                *(unsigned*)&pH[off] = (unsigned)h0 | ((unsigned)h1 << 16);
                *(unsigned*)&pL[off] = (unsigned)l0 | ((unsigned)l1 << 16);
            }
        }
        __syncthreads();
    }

    // --- GEMM-D: h = tanh([x|pooled] @ [Wih;Whh] + b), split-bf16 ---
    bf16x8 ah[8], al[8];
    #pragma unroll
    for (int kt = 0; kt < 4; ++kt) {   // x part from preloaded registers
        const float4 v0 = xr[kt * 2 + 0];
        const float4 v1 = xr[kt * 2 + 1];
        const float vv[8] = {v0.x, v0.y, v0.z, v0.w, v1.x, v1.y, v1.z, v1.w};
        bf16x8 hfr, lfr;
        #pragma unroll
        for (int i = 0; i < 8; ++i) {
            const __bf16 hb = (__bf16)vv[i];
            hfr[i] = hb;
            lfr[i] = (__bf16)(vv[i] - (float)hb);
        }
        ah[kt] = hfr; al[kt] = lfr;
    }
    if (any) {
        #pragma unroll
        for (int kt = 4; kt < 8; ++kt) {
            const unsigned off = SWZ(lrow, (kt - 4) * 64 + lgrp * 16);
            ah[kt] = *(const bf16x8*)&pH[off];
            al[kt] = *(const bf16x8*)&pL[off];
        }
    }
    float hv[2][4];
    #pragma unroll
    for (int nn = 0; nn < 2; ++nn) {
        const int nt = w * 2 + nn;
        f32x4 acc = {0.f, 0.f, 0.f, 0.f};
        #pragma unroll
        for (int kt = 0; kt < 4; ++kt) {
            const bf16x8 bh = *(const bf16x8*)&WdHi[((nt * 8 + kt) * 64 + lane) * 8];
            const bf16x8 bl = *(const bf16x8*)&WdLo[((nt * 8 + kt) * 64 + lane) * 8];
            acc = __builtin_amdgcn_mfma_f32_16x16x32_bf16(ah[kt], bh, acc, 0, 0, 0);
            acc = __builtin_amdgcn_mfma_f32_16x16x32_bf16(ah[kt], bl, acc, 0, 0, 0);
            acc = __builtin_amdgcn_mfma_f32_16x16x32_bf16(al[kt], bh, acc, 0, 0, 0);
        }
        if (any) {
            #pragma unroll
            for (int kt = 4; kt < 8; ++kt) {
                const bf16x8 bh = *(const bf16x8*)&WdHi[((nt * 8 + kt) * 64 + lane) * 8];
                const bf16x8 bl = *(const bf16x8*)&WdLo[((nt * 8 + kt) * 64 + lane) * 8];
                acc = __builtin_amdgcn_mfma_f32_16x16x32_bf16(ah[kt], bh, acc, 0, 0, 0);
                acc = __builtin_amdgcn_mfma_f32_16x16x32_bf16(ah[kt], bl, acc, 0, 0, 0);
                acc = __builtin_amdgcn_mfma_f32_16x16x32_bf16(al[kt], bh, acc, 0, 0, 0);
            }
        }
        const float b = bias[nt * 16 + lrow];
        #pragma unroll
        for (int r = 0; r < 4; ++r)
            hv[nn][r] = fast_tanh(acc[r] + b);
    }

    if (h_out != nullptr) {
        #pragma unroll
        for (int nn = 0; nn < 2; ++nn) {
            const int nt = w * 2 + nn;
            #pragma unroll
            for (int r = 0; r < 4; ++r)
                h_out[(nbase + lgrp * 4 + r) * HH + nt * 16 + lrow] = hv[nn][r];
        }
    }
    if (Hp_out != nullptr) {
        // epilogue: Hp_next = h @ Wg via LDS transpose (pH/pL reused)
        __syncthreads();
        #pragma unroll
        for (int nn = 0; nn < 2; ++nn) {
            #pragma unroll
            for (int r = 0; r < 4; ++r) {
                const int row = lgrp * 4 + r;               // node in block
                const int col = (w * 2 + nn) * 16 + lrow;   // h column
                const unsigned short hb = f2bfbits(hv[nn][r]);
                const unsigned short lb = f2bfbits(hv[nn][r] - bfbits2f(hb));
                const unsigned off = SWZ(row, col * 2);
                *(unsigned short*)&pH[off] = hb;
                *(unsigned short*)&pL[off] = lb;
            }
        }
        __syncthreads();
        bf16x8 aHh[4], aLh[4];
        #pragma unroll
        for (int kt = 0; kt < 4; ++kt) {
            const unsigned off = SWZ(lrow, kt * 64 + lgrp * 16);
            aHh[kt] = *(const bf16x8*)&pH[off];
            aLh[kt] = *(const bf16x8*)&pL[off];
        }
        #pragma unroll
        for (int nn = 0; nn < 2; ++nn) {
            const int nt = w * 2 + nn;
            f32x4 acc = {0.f, 0.f, 0.f, 0.f};
            #pragma unroll
            for (int kt = 0; kt < 4; ++kt) {
                const bf16x8 bh = *(const bf16x8*)&WgHi[((nt * 4 + kt) * 64 + lane) * 8];
                const bf16x8 bl = *(const bf16x8*)&WgLo[((nt * 4 + kt) * 64 + lane) * 8];
                acc = __builtin_amdgcn_mfma_f32_16x16x32_bf16(aHh[kt], bh, acc, 0, 0, 0);
                acc = __builtin_amdgcn_mfma_f32_16x16x32_bf16(aHh[kt], bl, acc, 0, 0, 0);
                acc = __builtin_amdgcn_mfma_f32_16x16x32_bf16(aLh[kt], bh, acc, 0, 0, 0);
            }
            #pragma unroll
            for (int r = 0; r < 4; ++r)
                Hp_out[(nbase + lgrp * 4 + r) * HH + nt * 16 + lrow] = acc[r];
        }
    }
}

extern "C" void kernel_launch(void* const* d_in, const int* in_sizes, int n_in,
                              void* d_out, int out_size, void* d_ws, size_t ws_size,
                              hipStream_t stream) {
    const float* nf   = (const float*)d_in[0];
    const int*   cidx = (const int*)d_in[1];
    const unsigned char* mraw = (const unsigned char*)d_in[2];
    const float* A_c  = (const float*)d_in[3];
    const float* Wg   = (const float*)d_in[4];
    const float* Wih  = (const float*)d_in[5];
    const float* Whh  = (const float*)d_in[6];
    const float* bih  = (const float*)d_in[7];
    const float* bhh  = (const float*)d_in[8];
    float* outp = (float*)d_out;

    char* ws = (char*)d_ws;
    unsigned char* mbits = (unsigned char*)ws;                               // 96 KB
    unsigned short* WgHi = (unsigned short*)(ws + (128 << 10));              // 32 KB
    unsigned short* WgLo = (unsigned short*)(ws + (160 << 10));              // 32 KB
    unsigned short* WdHi = (unsigned short*)(ws + (192 << 10));              // 64 KB
    unsigned short* WdLo = (unsigned short*)(ws + (256 << 10));              // 64 KB
    float* bias          = (float*)(ws + (320 << 10));                       // 512 B
    float* HpA           = (float*)(ws + (1 << 20));                         // 8 MB
    float* HpB           = (float*)(ws + (1 << 20) + (8 << 20));             // 8 MB

    prologue_kernel<<<(LL * NN) / 256, 256, 0, stream>>>(
        mraw, Wg, Wih, Whh, bih, bhh, mbits, WgHi, WgLo, WdHi, WdLo, bias);

    // Levels reversed; s=0 (level L-1) has all-false masks -> Hp_in passed
    // as nullptr (skips all phase-A staging). Epilogue of level s writes Hp
    // for level s+1 into the other Hp buffer (ping-pong). Intermediate h
    // never hits global.
    for (int s = 0; s < LL; ++s) {
        const int l = LL - 1 - s;
        float* hp_in  = (s & 1) ? HpB : HpA;
        float* hp_out = (s & 1) ? HpA : HpB;
        level_kernel<<<NN / BN, 256, 0, stream>>>(
            nf   + (size_t)l * NN * FF,
            cidx + (size_t)l * NN * CC,
            mbits + (size_t)l * NN,
            (s == 0) ? nullptr : hp_in,
            A_c  + (size_t)l * NN * CC * CC,
            WgHi, WgLo, WdHi, WdLo, bias,
            (s == LL - 1) ? outp : nullptr,
            (s == LL - 1) ? nullptr : hp_out);
    }
}